// Round 11
// baseline (135.886 us; speedup 1.0000x reference)
//
#include <hip/hip_runtime.h>

typedef __bf16 bf16x8 __attribute__((ext_vector_type(8)));
typedef float f32x4 __attribute__((ext_vector_type(4)));

#define C_IN 128
#define HW_IN 3136      // 56*56 xt rows per image
#define K_OUT 256
#define OWP 56          // padded output width
#define M_PER_IMG 3024  // 54*56 padded-m rows per image
#define KG 1152         // 128*9
#define OUT_HW 2916     // 54*54
#define NBLK 3024       // 756 spatial tiles x 4 kch tiles = 8*378

// ws layout (bytes):
//   [0,4)          : absmax bits (uint)
//   [4096, 593920) : Bt bf16 [256][1152], kk = (r*3+s)*128 + c
//   [593920, ...)  : xt bf16 [n][hw:3136][c:128] + >=1KB tail pad

static __device__ __forceinline__ unsigned short f2bf(float f) {
  unsigned u = __float_as_uint(f);
  u += 0x7FFFu + ((u >> 16) & 1);   // RNE
  return (unsigned short)(u >> 16);
}

static __device__ __forceinline__ void gload16(const unsigned short* g, unsigned short* l) {
  __builtin_amdgcn_global_load_lds(
      (const __attribute__((address_space(1))) unsigned int*)g,
      (__attribute__((address_space(3))) unsigned int*)l, 16, 0, 0);
}

__global__ __launch_bounds__(256) void k_quant(const float* __restrict__ w,
                                               const unsigned* __restrict__ mx,
                                               unsigned short* __restrict__ bt) {
  const int idx = blockIdx.x * 256 + threadIdx.x;  // < 294912
  const float thr = 0.05f * __uint_as_float(*mx);
  const int k = idx / KG;
  const int j = idx - k * KG;
  const int rs = j >> 7;
  const int c = j & 127;
  const float v = w[k * KG + c * 9 + rs];
  float q = 0.f;
  if (v > thr) q = 1.f;
  else if (v < -thr) q = -1.f;
  bt[idx] = f2bf(q);
}

// x fp32 NCHW -> xt bf16 [n][hw][c] (float4 loads, LDS transpose) + fused
// |w| absmax (each thread <=1 elem, block-reduce, one atomicMax).
__global__ __launch_bounds__(256) void k_xt(const float* __restrict__ x,
                                            const float* __restrict__ w,
                                            unsigned short* __restrict__ xt,
                                            unsigned* __restrict__ mx) {
  __shared__ unsigned short tile[8192];  // [j:64][c:128], phys c = c ^ j
  __shared__ float red[256];
  const int t = threadIdx.x;
  {
    const int i = blockIdx.x * 256 + t;
    red[t] = (i < 294912) ? fabsf(w[i]) : 0.f;
    __syncthreads();
    for (int s = 128; s > 0; s >>= 1) {
      if (t < s) red[t] = fmaxf(red[t], red[t + s]);
      __syncthreads();
    }
    if (t == 0) atomicMax(mx, __float_as_uint(red[0]));
  }
  const int n = blockIdx.x / 49;
  const int hw0 = (blockIdx.x - n * 49) * 64;
  const int q4 = t & 15;
  const int c0 = t >> 4;
  const float* xp = x + (size_t)n * (C_IN * HW_IN) + hw0 + q4 * 4;
#pragma unroll
  for (int it = 0; it < 8; ++it) {
    const int c = it * 16 + c0;
    const float4 v = *(const float4*)(xp + (size_t)c * HW_IN);
    const int j0 = q4 * 4;
    tile[(j0 + 0) * 128 + (c ^ (j0 + 0))] = f2bf(v.x);
    tile[(j0 + 1) * 128 + (c ^ (j0 + 1))] = f2bf(v.y);
    tile[(j0 + 2) * 128 + (c ^ (j0 + 2))] = f2bf(v.z);
    tile[(j0 + 3) * 128 + (c ^ (j0 + 3))] = f2bf(v.w);
  }
  __syncthreads();
  const int jj = t >> 2;
  const int q = t & 3;
  unsigned short v[32] __attribute__((aligned(16)));
#pragma unroll
  for (int i = 0; i < 32; ++i)
    v[i] = tile[jj * 128 + ((q * 32 + i) ^ jj)];
  uint4* dst = (uint4*)(xt + (size_t)(n * HW_IN + hw0 + jj) * 128 + q * 32);
#pragma unroll
  for (int u = 0; u < 4; ++u)
    dst[u] = *(const uint4*)&v[u * 8];
}

// Conv GEMM: R7 geometry (64 kch x 128 sp, 4 waves, 24KB LDS, 4 blocks/CU)
// + R8's counted-vmcnt pipeline at HALF-K granularity: 36 steps of K=32,
// each half double-buffered in 2x12KB (total LDS unchanged vs R7).
// Per half: bar -> STAGE(h+1, 3 gloads) -> vmcnt(3) -> bar -> 6 ds_read + 8 MFMA.
__global__ __launch_bounds__(256, 4) void k_conv(const unsigned short* __restrict__ xt,
                                                 const unsigned short* __restrict__ bt,
                                                 const float* __restrict__ bias,
                                                 float* __restrict__ out) {
  __shared__ unsigned short As[2][2048];   // [buf][64 rows x 32 kk] 64B rows
  __shared__ unsigned short Xs[2][4096];   // [buf][128 rows x 32 kk]
  const int t = threadIdx.x;
  const int g = (blockIdx.x & 7) * 378 + (blockIdx.x >> 3);  // T1 (3024 = 8*378)
  const int kcht = g & 3;
  const int spt = g >> 2;

  // ---- staging: thread t -> row t>>2 (0..63), chunk t&3; source pre-swizzled
  const int sr4 = t >> 2;
  const int sc4 = t & 3;
  const int ssw4 = ((sc4 ^ (sr4 & 3)) << 3);   // shorts
  const unsigned short* asrc = bt + (size_t)(kcht * 64 + sr4) * KG + ssw4;
  const unsigned short* xsrc[2];
#pragma unroll
  for (int u = 0; u < 2; ++u) {
    const int m = spt * 128 + u * 64 + sr4;
    xsrc[u] = xt + (size_t)(m + 112 * (m / M_PER_IMG)) * 128 + ssw4;
  }
  const int wv = t >> 6;
  const int wvb = wv * 512;   // wave-uniform dest base (shorts)

  // ---- fragment setup
  const int l = t & 63;
  const int lr = l & 15;
  const int hh = l >> 4;
  const int fsw = ((hh ^ (lr & 3)) << 3);   // phys chunk offset (shorts)

  f32x4 acc[4][2];
#pragma unroll
  for (int f = 0; f < 4; ++f)
#pragma unroll
    for (int fx = 0; fx < 2; ++fx)
      acc[f][fx] = (f32x4){0.f, 0.f, 0.f, 0.f};

  // stage half h (K columns h*32..h*32+31) into buffer b: 3 gloads
  auto STAGE = [&](int h, int b) __attribute__((always_inline)) {
    const int kt = h >> 1;
    const int rs = kt >> 1;
    const int rd = rs / 3;
    const int rm = rs - rd * 3;
    const int xoff = (rd * 56 + rm) * 128 + ((kt & 1) << 6) + ((h & 1) << 5);
    gload16(asrc + (h << 5), &As[b][wvb]);
    gload16(xsrc[0] + xoff, &Xs[b][wvb]);
    gload16(xsrc[1] + xoff, &Xs[b][2048 + wvb]);
  };

  STAGE(0, 0);
#pragma unroll 4
  for (int h = 0; h < 36; ++h) {
    const int b = h & 1;
    __builtin_amdgcn_s_barrier();          // all waves done reading buf b^1 (iter h-1)
    if (h < 35) {
      STAGE(h + 1, b ^ 1);
      asm volatile("s_waitcnt vmcnt(3)" ::: "memory");  // h's 3 loads landed
    } else {
      asm volatile("s_waitcnt vmcnt(0)" ::: "memory");
    }
    __builtin_amdgcn_s_barrier();          // h's data visible to all waves
    __builtin_amdgcn_sched_barrier(0);     // pin ds_reads below barrier
    bf16x8 af[4], xf[2];
#pragma unroll
    for (int f = 0; f < 4; ++f)
      af[f] = *(const bf16x8*)&As[b][((f * 16 + lr) << 5) + fsw];
#pragma unroll
    for (int fx = 0; fx < 2; ++fx)
      xf[fx] = *(const bf16x8*)&Xs[b][((wv * 32 + fx * 16 + lr) << 5) + fsw];
    __builtin_amdgcn_s_setprio(1);
#pragma unroll
    for (int f = 0; f < 4; ++f)
#pragma unroll
      for (int fx = 0; fx < 2; ++fx)
        acc[f][fx] = __builtin_amdgcn_mfma_f32_16x16x32_bf16(af[f], xf[fx], acc[f][fx], 0, 0, 0);
    __builtin_amdgcn_s_setprio(0);
  }

  // ---- epilogue: D row=(hh*4+rg) -> kch; col=lr -> spatial
  float bv[4][4];
#pragma unroll
  for (int f = 0; f < 4; ++f)
#pragma unroll
    for (int rg = 0; rg < 4; ++rg)
      bv[f][rg] = bias[kcht * 64 + f * 16 + hh * 4 + rg];

#pragma unroll
  for (int fx = 0; fx < 2; ++fx) {
    const int m = spt * 128 + wv * 32 + fx * 16 + lr;
    const int ni = m / M_PER_IMG;
    const int rem = m - ni * M_PER_IMG;
    const int oh = rem / OWP;
    const int ow = rem - oh * OWP;
    if (ow < 54) {
      float* op = out + (size_t)ni * (K_OUT * OUT_HW) + oh * 54 + ow;
#pragma unroll
      for (int f = 0; f < 4; ++f) {
        const int kbase = kcht * 64 + f * 16 + hh * 4;
#pragma unroll
        for (int rg = 0; rg < 4; ++rg)
          op[(size_t)(kbase + rg) * OUT_HW] = acc[f][fx][rg] + bv[f][rg];
      }
    }
  }
}

extern "C" void kernel_launch(void* const* d_in, const int* in_sizes, int n_in,
                              void* d_out, int out_size, void* d_ws, size_t ws_size,
                              hipStream_t stream) {
  const float* x = (const float*)d_in[0];
  const float* w = (const float*)d_in[1];
  const float* bias = (const float*)d_in[2];
  float* out = (float*)d_out;
  unsigned char* ws = (unsigned char*)d_ws;
  unsigned* mx = (unsigned*)ws;
  unsigned short* bt = (unsigned short*)(ws + 4096);
  unsigned short* xt = (unsigned short*)(ws + 593920);

  hipMemsetAsync(mx, 0, 4, stream);
  k_xt<<<32 * 49, 256, 0, stream>>>(x, w, xt, mx);   // transpose + fused absmax
  k_quant<<<1152, 256, 0, stream>>>(w, mx, bt);
  k_conv<<<NBLK, 256, 0, stream>>>(xt, bt, bias, out);
}

// Round 12
// 102.947 us; speedup vs baseline: 1.3200x; 1.3200x over previous
//
#include <hip/hip_runtime.h>

typedef __bf16 bf16x8 __attribute__((ext_vector_type(8)));
typedef float f32x4 __attribute__((ext_vector_type(4)));

#define C_IN 128
#define HW_IN 3136      // 56*56 xt rows per image
#define K_OUT 256
#define OWP 56          // padded output width
#define M_PER_IMG 3024  // 54*56 padded-m rows per image
#define KG 1152         // 128*9
#define OUT_HW 2916     // 54*54
#define NBLK 1512       // 756 spatial tiles x 2 kch tiles = 8*189

// ws layout (bytes):
//   [0,4)          : absmax bits (uint)
//   [4096, 593920) : Bt bf16 [256][1152], kk = (r*3+s)*128 + c
//   [593920, ...)  : xt bf16 [n][hw:3136][c:128] + >=1KB tail pad

static __device__ __forceinline__ unsigned short f2bf(float f) {
  unsigned u = __float_as_uint(f);
  u += 0x7FFFu + ((u >> 16) & 1);   // RNE
  return (unsigned short)(u >> 16);
}

static __device__ __forceinline__ void gload16(const unsigned short* g, unsigned short* l) {
  __builtin_amdgcn_global_load_lds(
      (const __attribute__((address_space(1))) unsigned int*)g,
      (__attribute__((address_space(3))) unsigned int*)l, 16, 0, 0);
}

__global__ __launch_bounds__(256) void k_quant(const float* __restrict__ w,
                                               const unsigned* __restrict__ mx,
                                               unsigned short* __restrict__ bt) {
  const int idx = blockIdx.x * 256 + threadIdx.x;  // < 294912
  const float thr = 0.05f * __uint_as_float(*mx);
  const int k = idx / KG;
  const int j = idx - k * KG;
  const int rs = j >> 7;
  const int c = j & 127;
  const float v = w[k * KG + c * 9 + rs];
  float q = 0.f;
  if (v > thr) q = 1.f;
  else if (v < -thr) q = -1.f;
  bt[idx] = f2bf(q);
}

// x fp32 NCHW -> xt bf16 [n][hw][c] (float4 loads, LDS transpose) + fused
// |w| absmax (each thread <=1 elem, block-reduce, one atomicMax).
__global__ __launch_bounds__(256) void k_xt(const float* __restrict__ x,
                                            const float* __restrict__ w,
                                            unsigned short* __restrict__ xt,
                                            unsigned* __restrict__ mx) {
  __shared__ unsigned short tile[8192];  // [j:64][c:128], phys c = c ^ j
  __shared__ float red[256];
  const int t = threadIdx.x;
  {
    const int i = blockIdx.x * 256 + t;
    red[t] = (i < 294912) ? fabsf(w[i]) : 0.f;
    __syncthreads();
    for (int s = 128; s > 0; s >>= 1) {
      if (t < s) red[t] = fmaxf(red[t], red[t + s]);
      __syncthreads();
    }
    if (t == 0) atomicMax(mx, __float_as_uint(red[0]));
  }
  const int n = blockIdx.x / 49;
  const int hw0 = (blockIdx.x - n * 49) * 64;
  const int q4 = t & 15;
  const int c0 = t >> 4;
  const float* xp = x + (size_t)n * (C_IN * HW_IN) + hw0 + q4 * 4;
#pragma unroll
  for (int it = 0; it < 8; ++it) {
    const int c = it * 16 + c0;
    const float4 v = *(const float4*)(xp + (size_t)c * HW_IN);
    const int j0 = q4 * 4;
    tile[(j0 + 0) * 128 + (c ^ (j0 + 0))] = f2bf(v.x);
    tile[(j0 + 1) * 128 + (c ^ (j0 + 1))] = f2bf(v.y);
    tile[(j0 + 2) * 128 + (c ^ (j0 + 2))] = f2bf(v.z);
    tile[(j0 + 3) * 128 + (c ^ (j0 + 3))] = f2bf(v.w);
  }
  __syncthreads();
  const int jj = t >> 2;
  const int q = t & 3;
  unsigned short v[32] __attribute__((aligned(16)));
#pragma unroll
  for (int i = 0; i < 32; ++i)
    v[i] = tile[jj * 128 + ((q * 32 + i) ^ jj)];
  uint4* dst = (uint4*)(xt + (size_t)(n * HW_IN + hw0 + jj) * 128 + q * 32);
#pragma unroll
  for (int u = 0; u < 4; ++u)
    dst[u] = *(const uint4*)&v[u * 8];
}

// Conv GEMM, LDS-traffic-minimized geometry:
//   block 128 kch x 128 sp x BK=64; 4 waves as 2x2; wave tile 64x64 with
//   4x4 fragment blocking (16 MFMA per af-load, af[4] + xf[2]-halves).
//   LDS traffic: 46.9 B/kFLOP vs R7's 70 (stage 15.6 + read 31.25).
//   R7's proven minimal loop + 8-chunk XOR swizzle (2-way-free reads).
__global__ __launch_bounds__(256, 4) void k_conv(const unsigned short* __restrict__ xt,
                                                 const unsigned short* __restrict__ bt,
                                                 const float* __restrict__ bias,
                                                 float* __restrict__ out) {
  __shared__ unsigned short As[8192];   // 128 rows x 64 kk, 8-chunk XOR swizzle
  __shared__ unsigned short Xs[8192];   // 128 rows x 64 kk
  const int t = threadIdx.x;
  const int g = (blockIdx.x & 7) * 189 + (blockIdx.x >> 3);  // T1 (1512 = 8*189)
  const int kcht = g & 1;    // kch tile fastest -> X panel L2 reuse per XCD
  const int spt = g >> 1;

  // ---- staging: thread t -> row srow (0..31), chunk sch (0..7); pre-swizzled src
  const int srow = t >> 3;
  const int sch = t & 7;
  const int ssw = ((sch ^ (srow & 7)) << 3);
  const unsigned short* asrc = bt + (size_t)(kcht * 128 + srow) * KG + ssw;  // +u*32*KG
  const unsigned short* xsrc[4];
#pragma unroll
  for (int q = 0; q < 4; ++q) {
    const int m = spt * 128 + q * 32 + srow;    // q*32 keeps (row&7) invariant
    xsrc[q] = xt + (size_t)(m + 112 * (m / M_PER_IMG)) * 128 + ssw;
  }
  const int wv = t >> 6;
  const int wvb = wv * 512;   // wave-uniform dest base (shorts)

  // ---- fragment setup: wave (wr,wc) owns kch rows wr*64.., sp cols wc*64..
  const int l = t & 63;
  const int wr = wv >> 1;
  const int wc = wv & 1;
  const int lr = l & 15;
  const int hh = l >> 4;
  const int lsw = lr & 7;

  f32x4 acc[4][4];
#pragma unroll
  for (int f = 0; f < 4; ++f)
#pragma unroll
    for (int fx = 0; fx < 4; ++fx)
      acc[f][fx] = (f32x4){0.f, 0.f, 0.f, 0.f};

  for (int kt = 0; kt < 18; ++kt) {
    const int rs = kt >> 1;
    const int rd = rs / 3;
    const int rm = rs - rd * 3;
    const int xoff = (rd * 56 + rm) * 128 + ((kt & 1) << 6);
    const int aoff = kt << 6;
    __builtin_amdgcn_s_barrier();            // all waves done reading prev tile
    gload16(asrc + aoff, &As[wvb]);
    gload16(asrc + (size_t)32 * KG + aoff, &As[2048 + wvb]);
    gload16(asrc + (size_t)64 * KG + aoff, &As[4096 + wvb]);
    gload16(asrc + (size_t)96 * KG + aoff, &As[6144 + wvb]);
    gload16(xsrc[0] + xoff, &Xs[wvb]);
    gload16(xsrc[1] + xoff, &Xs[2048 + wvb]);
    gload16(xsrc[2] + xoff, &Xs[4096 + wvb]);
    gload16(xsrc[3] + xoff, &Xs[6144 + wvb]);
    asm volatile("s_waitcnt vmcnt(0)" ::: "memory");
    __builtin_amdgcn_s_barrier();            // staged data visible
    __builtin_amdgcn_sched_barrier(0);       // pin ds_reads below barrier
#pragma unroll
    for (int ks = 0; ks < 2; ++ks) {
      const int ch = (((ks << 2) + hh) ^ lsw) << 3;
      bf16x8 af[4];
#pragma unroll
      for (int f = 0; f < 4; ++f)
        af[f] = *(const bf16x8*)&As[((wr * 64 + f * 16 + lr) << 6) + ch];
#pragma unroll
      for (int half = 0; half < 2; ++half) {
        bf16x8 xf[2];
#pragma unroll
        for (int j = 0; j < 2; ++j)
          xf[j] = *(const bf16x8*)&Xs[((wc * 64 + (half * 2 + j) * 16 + lr) << 6) + ch];
        __builtin_amdgcn_s_setprio(1);
#pragma unroll
        for (int f = 0; f < 4; ++f)
#pragma unroll
          for (int j = 0; j < 2; ++j)
            acc[f][half * 2 + j] =
                __builtin_amdgcn_mfma_f32_16x16x32_bf16(af[f], xf[j], acc[f][half * 2 + j], 0, 0, 0);
        __builtin_amdgcn_s_setprio(0);
      }
    }
  }

  // ---- epilogue: D row=(hh*4+rg) -> kch; col=lr -> spatial
  float bv[4][4];
#pragma unroll
  for (int f = 0; f < 4; ++f)
#pragma unroll
    for (int rg = 0; rg < 4; ++rg)
      bv[f][rg] = bias[kcht * 128 + wr * 64 + f * 16 + hh * 4 + rg];

#pragma unroll
  for (int fx = 0; fx < 4; ++fx) {
    const int m = spt * 128 + wc * 64 + fx * 16 + lr;
    const int ni = m / M_PER_IMG;
    const int rem = m - ni * M_PER_IMG;
    const int oh = rem / OWP;
    const int ow = rem - oh * OWP;
    if (ow < 54) {
      float* op = out + (size_t)ni * (K_OUT * OUT_HW) + oh * 54 + ow;
#pragma unroll
      for (int f = 0; f < 4; ++f) {
        const int kbase = kcht * 128 + wr * 64 + f * 16 + hh * 4;
#pragma unroll
        for (int rg = 0; rg < 4; ++rg)
          op[(size_t)(kbase + rg) * OUT_HW] = acc[f][fx][rg] + bv[f][rg];
      }
    }
  }
}

extern "C" void kernel_launch(void* const* d_in, const int* in_sizes, int n_in,
                              void* d_out, int out_size, void* d_ws, size_t ws_size,
                              hipStream_t stream) {
  const float* x = (const float*)d_in[0];
  const float* w = (const float*)d_in[1];
  const float* bias = (const float*)d_in[2];
  float* out = (float*)d_out;
  unsigned char* ws = (unsigned char*)d_ws;
  unsigned* mx = (unsigned*)ws;
  unsigned short* bt = (unsigned short*)(ws + 4096);
  unsigned short* xt = (unsigned short*)(ws + 593920);

  hipMemsetAsync(mx, 0, 4, stream);
  k_xt<<<32 * 49, 256, 0, stream>>>(x, w, xt, mx);   // transpose + fused absmax
  k_quant<<<1152, 256, 0, stream>>>(w, mx, bt);
  k_conv<<<NBLK, 256, 0, stream>>>(xt, bt, bias, out);
}